// Round 7
// baseline (130.301 us; speedup 1.0000x reference)
//
#include <hip/hip_runtime.h>

#define NDOF 7
#define NPARK 5                     // links 0..4 parked in LDS; 5,6 fused in regs
#define BLK 128                     // threads per block (2 waves)
#define RPB 256                     // rows per block (2 rows per thread)
#define CST_STRIDE 24               // floats per dof block (= 6 float4)
#define CST_TOT (NDOF * CST_STRIDE) // 168
#define SF_FLOATS (NPARK * 6 * RPB) // 7680 floats = 30720 B parked wrenches

// ---------- tiny vec3 ----------
struct V3 { float x, y, z; };
__device__ __forceinline__ V3 operator+(V3 a, V3 b) { return {a.x + b.x, a.y + b.y, a.z + b.z}; }
__device__ __forceinline__ V3 operator-(V3 a, V3 b) { return {a.x - b.x, a.y - b.y, a.z - b.z}; }
__device__ __forceinline__ V3 operator*(float s, V3 a) { return {s * a.x, s * a.y, s * a.z}; }
__device__ __forceinline__ V3 cross(V3 a, V3 b) {
    return {a.y * b.z - a.z * b.y, a.z * b.x - a.x * b.z, a.x * b.y - a.y * b.x};
}
__device__ __forceinline__ float dot(V3 a, V3 b) { return a.x * b.x + a.y * b.y + a.z * b.z; }

// ---------- prep: pack per-dof constants into d_ws ----------
// per dof d (24 floats): [0:9) F columns (column-major), [9:12) p,
// [12:18) Io6=I00,I01,I02,I11,I12,I22, [18] m, [19:22) mc, [22] damp, [23] pad
__global__ void rnea_prep(const float* __restrict__ rot_fix,
                          const float* __restrict__ trans_fix,
                          const float* __restrict__ mass_g,
                          const float* __restrict__ com_g,
                          const float* __restrict__ inertia_g,
                          const float* __restrict__ damping_g,
                          float* __restrict__ cst) {
    const int d = threadIdx.x;
    if (d >= NDOF) return;
    float* o = cst + d * CST_STRIDE;
    const float* F = rot_fix + (1 + d) * 9;
#pragma unroll
    for (int j = 0; j < 3; j++)
#pragma unroll
        for (int i = 0; i < 3; i++) o[j * 3 + i] = F[i * 3 + j];  // column-major
#pragma unroll
    for (int i = 0; i < 3; i++) o[9 + i] = trans_fix[(1 + d) * 3 + i];
    const float m = mass_g[1 + d];
    const float c0 = com_g[(1 + d) * 3 + 0];
    const float c1 = com_g[(1 + d) * 3 + 1];
    const float c2 = com_g[(1 + d) * 3 + 2];
    const float* I = inertia_g + (1 + d) * 9;
    o[12] = I[0] + m * (c1 * c1 + c2 * c2);
    o[13] = I[1] - m * c0 * c1;
    o[14] = I[2] - m * c0 * c2;
    o[15] = I[4] + m * (c0 * c0 + c2 * c2);
    o[16] = I[5] - m * c1 * c2;
    o[17] = I[8] + m * (c0 * c0 + c1 * c1);
    o[18] = m;
    o[19] = m * c0;
    o[20] = m * c1;
    o[21] = m * c2;
    o[22] = damping_g[d];
    o[23] = 0.f;
}

// AX: 0 = +z, 1 = +y, 2 = -y   (joint_axes is a literal in the reference)
template <int AX>
__device__ __forceinline__ void make_R(V3 Fc0, V3 Fc1, V3 Fc2, float s, float c,
                                       V3& R0, V3& R1, V3& R2) {
    if (AX == 0) {          // Rq_z cols: (c,s,0), (-s,c,0), (0,0,1)
        R0 = c * Fc0 + s * Fc1;
        R1 = c * Fc1 - s * Fc0;
        R2 = Fc2;
    } else if (AX == 1) {   // Rq_y cols: (c,0,-s), (0,1,0), (s,0,c)
        R0 = c * Fc0 - s * Fc2;
        R1 = Fc1;
        R2 = s * Fc0 + c * Fc2;
    } else {                // Rq_-y cols: (c,0,s), (0,1,0), (-s,0,c)
        R0 = c * Fc0 + s * Fc2;
        R1 = Fc1;
        R2 = c * Fc2 - s * Fc0;
    }
}

// fwd: constants passed BY VALUE so one LDS read serves both rows.
template <int AX>
__device__ __forceinline__ void fwd_step(float4 A0, float4 A1, float4 A2, float4 A3,
                                         float4 A4, float4 A5, float s, float c,
                                         float qd, float qdd, V3& vl, V3& va, V3& al,
                                         V3& aa, V3& fl, V3& fa) {
    const V3 Fc0{A0.x, A0.y, A0.z};
    const V3 Fc1{A0.w, A1.x, A1.y};
    const V3 Fc2{A1.z, A1.w, A2.x};
    const V3 p{A2.y, A2.z, A2.w};
    const float I00 = A3.x, I01 = A3.y, I02 = A3.z, I11 = A3.w, I12 = A4.x, I22 = A4.y;
    const float m = A4.z;
    const V3 mc{A4.w, A5.x, A5.y};

    V3 R0, R1, R2;
    make_R<AX>(Fc0, Fc1, Fc2, s, c, R0, R1, R2);

    // Rt(vl) + cross(-Rt p, Rt va) == Rt(vl + va x p)
    V3 w1 = vl + cross(va, p);
    V3 w2 = al + cross(aa, p);
    V3 nvl{dot(R0, w1), dot(R1, w1), dot(R2, w1)};
    V3 nva{dot(R0, va), dot(R1, va), dot(R2, va)};
    V3 nal{dot(R0, w2), dot(R1, w2), dot(R2, w2)};
    V3 naa{dot(R0, aa), dot(R1, aa), dot(R2, aa)};

    if (AX == 0) {          // jv=(0,0,qd): cross(v,jv)=(v.y*qd,-v.x*qd,0)
        va = {nva.x, nva.y, nva.z + qd};
        aa = {naa.x + va.y * qd, naa.y - va.x * qd, naa.z + qdd};
        vl = nvl;
        al = {nal.x + vl.y * qd, nal.y - vl.x * qd, nal.z};
    } else if (AX == 1) {   // jv=(0,qd,0): cross(v,jv)=(-v.z*qd,0,v.x*qd)
        va = {nva.x, nva.y + qd, nva.z};
        aa = {naa.x - va.z * qd, naa.y + qdd, naa.z + va.x * qd};
        vl = nvl;
        al = {nal.x - vl.z * qd, nal.y, nal.z + vl.x * qd};
    } else {                // jv=(0,-qd,0): cross(v,jv)=(v.z*qd,0,-v.x*qd)
        va = {nva.x, nva.y - qd, nva.z};
        aa = {naa.x + va.z * qd, naa.y - qdd, naa.z - va.x * qd};
        vl = nvl;
        al = {nal.x + vl.z * qd, nal.y, nal.z - vl.x * qd};
    }

    V3 Ial = m * al + cross(aa, mc);
    V3 Iaa = V3{I00 * aa.x + I01 * aa.y + I02 * aa.z,
                I01 * aa.x + I11 * aa.y + I12 * aa.z,
                I02 * aa.x + I12 * aa.y + I22 * aa.z} + cross(mc, al);
    V3 Ivl = m * vl + cross(va, mc);
    V3 Iva = V3{I00 * va.x + I01 * va.y + I02 * va.z,
                I01 * va.x + I11 * va.y + I12 * va.z,
                I02 * va.x + I12 * va.y + I22 * va.z} + cross(mc, vl);
    fl = Ial + cross(va, Ivl);
    fa = Iaa + cross(va, Iva) + cross(vl, Ivl);
}

// bwd: constants by value (shared across rows); updates carry, returns tau.
template <int AX>
__device__ __forceinline__ float bwd_core(float4 A0, float4 A1, float4 A2,
                                          float s, float c,
                                          V3 fl, V3 fa, V3& cl, V3& ca) {
    const V3 Fc0{A0.x, A0.y, A0.z};
    const V3 Fc1{A0.w, A1.x, A1.y};
    const V3 Fc2{A1.z, A1.w, A2.x};
    const V3 p{A2.y, A2.z, A2.w};

    V3 tl = fl + cl;
    V3 ta = fa + ca;
    float tau;
    if (AX == 0) tau = ta.z;
    else if (AX == 1) tau = ta.y;
    else tau = -ta.y;

    V3 R0, R1, R2;
    make_R<AX>(Fc0, Fc1, Fc2, s, c, R0, R1, R2);
    V3 nl = tl.x * R0 + tl.y * R1 + tl.z * R2;   // R @ tl (columns)
    V3 na = ta.x * R0 + ta.y * R1 + ta.z * R2 + cross(p, nl);
    cl = nl;
    ca = na;
    return tau;
}

// axis id for dof d: sequence z,y,z,-y,z,y,z -> 0,1,0,2,0,1,0
__device__ __forceinline__ int axid(int d) { return (d & 1) ? ((d == 3) ? 2 : 1) : 0; }

// ---------- main kernel ----------
// DUAL-ROW loop-form O(n) RNEA.  r6 counters: VALUBusy 60%, occupancy pinned
// at ~8 waves/CU regardless of LDS ceiling (3 vs 5 blocks/CU: no change) ->
// wave concurrency is not the available lever; per-wave ILP is.  r3's
// dual-row was null only because straight-line code doubling cancelled the
// wave halving (dur ~ code x waves); in loop form the body stays
// I$-resident, so two independent chains per thread now (1) fill issue
// during each other's stalls, (2) share the 6 ds_read_b128 constants per
// link (one read, two uses), (3) amortize loop/switch overhead.
// BLK=128, 256 rows/block: sF stays 30.7 KB (row A slot t, row B slot
// t+128).  cst restored to a prep kernel + one coalesced float4 burst
// (r6's inline prep made 3 waves idle at the barrier while 7 threads did
// ~40 divergent loads at block start).
__global__ __launch_bounds__(BLK) void rnea_main(
    const float* __restrict__ q_g, const float* __restrict__ qd_g,
    const float* __restrict__ qdd_g, const float* __restrict__ cst,
    float* __restrict__ out, int nbatch) {
    __shared__ __align__(16) float sC[CST_TOT];
    __shared__ float sF[SF_FLOATS];
    const int t = threadIdx.x;
    const int rowA = blockIdx.x * RPB + t;
    const int rowB = rowA + BLK;
    const bool okA = rowA < nbatch;
    const bool okB = rowB < nbatch;
    const int rcA = okA ? rowA : (nbatch - 1);
    const int rcB = okB ? rowB : (nbatch - 1);
    const size_t goA = (size_t)rcA * NDOF;
    const size_t goB = (size_t)rcB * NDOF;

    if (t < CST_TOT / 4)   // 42 float4 = one coalesced burst
        reinterpret_cast<float4*>(sC)[t] = reinterpret_cast<const float4*>(cst)[t];
    __syncthreads();

    // ---------------- forward pass: loop over parked links 0..4 ----------------
    V3 vlA{0.f, 0.f, 0.f}, vaA{0.f, 0.f, 0.f}, alA{0.f, 0.f, 9.81f}, aaA{0.f, 0.f, 0.f};
    V3 vlB{0.f, 0.f, 0.f}, vaB{0.f, 0.f, 0.f}, alB{0.f, 0.f, 9.81f}, aaB{0.f, 0.f, 0.f};
    float qAn = q_g[goA], qdAn = qd_g[goA], qddAn = qdd_g[goA];
    float qBn = q_g[goB], qdBn = qd_g[goB], qddBn = qdd_g[goB];
#pragma clang loop unroll(disable)
    for (int d = 0; d < NPARK; ++d) {
        const float qA = qAn, qdA = qdAn, qddA = qddAn;
        const float qB = qBn, qdB = qdBn, qddB = qddBn;
        qAn = q_g[goA + d + 1];   // prefetch next (d+1 <= 5)
        qdAn = qd_g[goA + d + 1];
        qddAn = qdd_g[goA + d + 1];
        qBn = q_g[goB + d + 1];
        qdBn = qd_g[goB + d + 1];
        qddBn = qdd_g[goB + d + 1];
        const float sA = __sinf(qA), cA = __cosf(qA);
        const float sB = __sinf(qB), cB = __cosf(qB);
        const float4* C4 = reinterpret_cast<const float4*>(sC) + d * 6;
        const float4 A0 = C4[0], A1 = C4[1], A2 = C4[2], A3 = C4[3], A4 = C4[4], A5 = C4[5];
        V3 flA, faA, flB, faB;
        switch (axid(d)) {
            case 0:
                fwd_step<0>(A0, A1, A2, A3, A4, A5, sA, cA, qdA, qddA, vlA, vaA, alA, aaA, flA, faA);
                fwd_step<0>(A0, A1, A2, A3, A4, A5, sB, cB, qdB, qddB, vlB, vaB, alB, aaB, flB, faB);
                break;
            case 1:
                fwd_step<1>(A0, A1, A2, A3, A4, A5, sA, cA, qdA, qddA, vlA, vaA, alA, aaA, flA, faA);
                fwd_step<1>(A0, A1, A2, A3, A4, A5, sB, cB, qdB, qddB, vlB, vaB, alB, aaB, flB, faB);
                break;
            default:
                fwd_step<2>(A0, A1, A2, A3, A4, A5, sA, cA, qdA, qddA, vlA, vaA, alA, aaA, flA, faA);
                fwd_step<2>(A0, A1, A2, A3, A4, A5, sB, cB, qdB, qddB, vlB, vaB, alB, aaB, flB, faB);
                break;
        }
        float* r = sF + d * 6 * RPB + t;   // [link][comp][slot]: lane-stride 1
        r[0 * RPB] = flA.x; r[1 * RPB] = flA.y; r[2 * RPB] = flA.z;
        r[3 * RPB] = faA.x; r[4 * RPB] = faA.y; r[5 * RPB] = faA.z;
        float* r2 = r + BLK;               // row B slots
        r2[0 * RPB] = flB.x; r2[1 * RPB] = flB.y; r2[2 * RPB] = flB.z;
        r2[3 * RPB] = faB.x; r2[4 * RPB] = faB.y; r2[5 * RPB] = faB.z;
    }

    // ---------------- peel: links 5,6 fwd -> immediate bwd in registers ----------
    const float q5A = qAn, qd5A = qdAn, qdd5A = qddAn;
    const float q5B = qBn, qd5B = qdBn, qdd5B = qddBn;
    const float q6A = q_g[goA + 6], qd6A = qd_g[goA + 6], qdd6A = qdd_g[goA + 6];
    const float q6B = q_g[goB + 6], qd6B = qd_g[goB + 6], qdd6B = qdd_g[goB + 6];
    const float s5A = __sinf(q5A), c5A = __cosf(q5A);
    const float s5B = __sinf(q5B), c5B = __cosf(q5B);
    const float s6A = __sinf(q6A), c6A = __cosf(q6A);
    const float s6B = __sinf(q6B), c6B = __cosf(q6B);
    float tau5A, tau6A, tau5B, tau6B;
    V3 clA{0.f, 0.f, 0.f}, caA{0.f, 0.f, 0.f};
    V3 clB{0.f, 0.f, 0.f}, caB{0.f, 0.f, 0.f};
    {
        const float4* C5 = reinterpret_cast<const float4*>(sC) + 5 * 6;
        const float4 B0 = C5[0], B1 = C5[1], B2 = C5[2], B3 = C5[3], B4 = C5[4], B5 = C5[5];
        const float4* C6 = reinterpret_cast<const float4*>(sC) + 6 * 6;
        const float4 D0 = C6[0], D1 = C6[1], D2 = C6[2], D3 = C6[3], D4 = C6[4], D5 = C6[5];
        V3 fl5A, fa5A, fl6A, fa6A, fl5B, fa5B, fl6B, fa6B;
        fwd_step<1>(B0, B1, B2, B3, B4, B5, s5A, c5A, qd5A, qdd5A, vlA, vaA, alA, aaA, fl5A, fa5A);
        fwd_step<1>(B0, B1, B2, B3, B4, B5, s5B, c5B, qd5B, qdd5B, vlB, vaB, alB, aaB, fl5B, fa5B);
        fwd_step<0>(D0, D1, D2, D3, D4, D5, s6A, c6A, qd6A, qdd6A, vlA, vaA, alA, aaA, fl6A, fa6A);
        fwd_step<0>(D0, D1, D2, D3, D4, D5, s6B, c6B, qd6B, qdd6B, vlB, vaB, alB, aaB, fl6B, fa6B);
        tau6A = bwd_core<0>(D0, D1, D2, s6A, c6A, fl6A, fa6A, clA, caA) + D5.z * qd6A;
        tau6B = bwd_core<0>(D0, D1, D2, s6B, c6B, fl6B, fa6B, clB, caB) + D5.z * qd6B;
        tau5A = bwd_core<1>(B0, B1, B2, s5A, c5A, fl5A, fa5A, clA, caA) + B5.z * qd5A;
        tau5B = bwd_core<1>(B0, B1, B2, s5B, c5B, fl5B, fa5B, clB, caB) + B5.z * qd5B;
        // note: damp lives at float offset 22 == component .z of float4 #5
    }

    // ---------------- backward pass: loop over parked links 4..0 ----------------
    // same-thread LDS reuse only -> no barrier; finished tau overwrites the
    // just-consumed fl.x slot so all global stores issue together below.
#pragma clang loop unroll(disable)
    for (int d = NPARK - 1; d >= 0; --d) {
        const float qA = q_g[goA + d];     // L1-hot reload
        const float qdA = qd_g[goA + d];
        const float qB = q_g[goB + d];
        const float qdB = qd_g[goB + d];
        const float sA = __sinf(qA), cA = __cosf(qA);
        const float sB = __sinf(qB), cB = __cosf(qB);
        const float4* C4 = reinterpret_cast<const float4*>(sC) + d * 6;
        const float4 A0 = C4[0], A1 = C4[1], A2 = C4[2];
        const float damp = sC[d * CST_STRIDE + 22];
        float* r = sF + d * 6 * RPB + t;
        const V3 flA{r[0 * RPB], r[1 * RPB], r[2 * RPB]};
        const V3 faA{r[3 * RPB], r[4 * RPB], r[5 * RPB]};
        float* r2 = r + BLK;
        const V3 flB{r2[0 * RPB], r2[1 * RPB], r2[2 * RPB]};
        const V3 faB{r2[3 * RPB], r2[4 * RPB], r2[5 * RPB]};
        float tauA, tauB;
        switch (axid(d)) {
            case 0:
                tauA = bwd_core<0>(A0, A1, A2, sA, cA, flA, faA, clA, caA);
                tauB = bwd_core<0>(A0, A1, A2, sB, cB, flB, faB, clB, caB);
                break;
            case 1:
                tauA = bwd_core<1>(A0, A1, A2, sA, cA, flA, faA, clA, caA);
                tauB = bwd_core<1>(A0, A1, A2, sB, cB, flB, faB, clB, caB);
                break;
            default:
                tauA = bwd_core<2>(A0, A1, A2, sA, cA, flA, faA, clA, caA);
                tauB = bwd_core<2>(A0, A1, A2, sB, cB, flB, faB, clB, caB);
                break;
        }
        r[0] = tauA + damp * qdA;          // park finished taus
        r2[0] = tauB + damp * qdB;
    }

    // ---------------- stores: all back-to-back (write-combine friendly) ---------
    if (okA) {
#pragma unroll
        for (int d = 0; d < NPARK; ++d) out[goA + d] = sF[d * 6 * RPB + t];
        out[goA + 5] = tau5A;
        out[goA + 6] = tau6A;
    }
    if (okB) {
#pragma unroll
        for (int d = 0; d < NPARK; ++d) out[goB + d] = sF[d * 6 * RPB + t + BLK];
        out[goB + 5] = tau5B;
        out[goB + 6] = tau6B;
    }
}

extern "C" void kernel_launch(void* const* d_in, const int* in_sizes, int n_in,
                              void* d_out, int out_size, void* d_ws, size_t ws_size,
                              hipStream_t stream) {
    const float* q = (const float*)d_in[0];
    const float* qd = (const float*)d_in[1];
    const float* qdd = (const float*)d_in[2];
    const float* rot_fix = (const float*)d_in[3];
    const float* trans_fix = (const float*)d_in[4];
    // d_in[5] = joint_axes: compile-time constant in the reference (z,y,z,-y,z,y,z)
    const float* mass = (const float*)d_in[6];
    const float* com = (const float*)d_in[7];
    const float* inertia = (const float*)d_in[8];
    const float* damping = (const float*)d_in[9];
    float* out = (float*)d_out;
    float* cst = (float*)d_ws;  // 7*24*4 = 672 B

    const int n_elem = in_sizes[0];  // B * 7
    const int B = n_elem / NDOF;
    const int grid = (B + RPB - 1) / RPB;

    rnea_prep<<<1, 64, 0, stream>>>(rot_fix, trans_fix, mass, com, inertia, damping, cst);
    rnea_main<<<grid, BLK, 0, stream>>>(q, qd, qdd, cst, out, B);
}

// Round 8
// 117.800 us; speedup vs baseline: 1.1061x; 1.1061x over previous
//
#include <hip/hip_runtime.h>

#define NDOF 7
#define NPARK 5                     // links 0..4 parked in LDS; 5,6 fused in regs
#define BLK 128                     // threads per block (2 waves)
#define RPB 256                     // rows per block (2 rows per thread: A, B)
#define CST_STRIDE 24               // floats per dof block (= 6 float4)
#define CST_TOT (NDOF * CST_STRIDE) // 168
#define SF_V2 (NPARK * 6 * BLK)     // f32x2 elements: 5*6*128*8B = 30720 B

// ---------- packed pair type: lane .x = row A, lane .y = row B ----------
// ext_vector_type keeps ops as <2 x float> in IR -> AMDGPU backend selects
// v_pk_fma_f32 / v_pk_add_f32 / v_pk_mul_f32 (gfx950 packed-FP32): one VALU
// instruction per 2-row operation.  This attacks the measured VALU-issue
// floor directly (r2-r7: dur x VALUBusy invariant at ~26 us-equiv).
typedef float f32x2 __attribute__((ext_vector_type(2)));

__device__ __forceinline__ f32x2 splat(float v) { f32x2 r; r.x = v; r.y = v; return r; }

struct PV3 { f32x2 x, y, z; };
__device__ __forceinline__ PV3 operator+(PV3 a, PV3 b) { return {a.x + b.x, a.y + b.y, a.z + b.z}; }
__device__ __forceinline__ PV3 operator-(PV3 a, PV3 b) { return {a.x - b.x, a.y - b.y, a.z - b.z}; }
__device__ __forceinline__ PV3 operator*(f32x2 s, PV3 a) { return {s * a.x, s * a.y, s * a.z}; }
__device__ __forceinline__ PV3 cross(PV3 a, PV3 b) {
    return {a.y * b.z - a.z * b.y, a.z * b.x - a.x * b.z, a.x * b.y - a.y * b.x};
}
__device__ __forceinline__ f32x2 dot(PV3 a, PV3 b) { return a.x * b.x + a.y * b.y + a.z * b.z; }
__device__ __forceinline__ PV3 uv(float x, float y, float z) { return {splat(x), splat(y), splat(z)}; }

// ---------- prep: pack per-dof constants into d_ws ----------
// per dof d (24 floats): [0:9) F columns (column-major), [9:12) p,
// [12:18) Io6=I00,I01,I02,I11,I12,I22, [18] m, [19:22) mc, [22] damp, [23] pad
__global__ void rnea_prep(const float* __restrict__ rot_fix,
                          const float* __restrict__ trans_fix,
                          const float* __restrict__ mass_g,
                          const float* __restrict__ com_g,
                          const float* __restrict__ inertia_g,
                          const float* __restrict__ damping_g,
                          float* __restrict__ cst) {
    const int d = threadIdx.x;
    if (d >= NDOF) return;
    float* o = cst + d * CST_STRIDE;
    const float* F = rot_fix + (1 + d) * 9;
#pragma unroll
    for (int j = 0; j < 3; j++)
#pragma unroll
        for (int i = 0; i < 3; i++) o[j * 3 + i] = F[i * 3 + j];  // column-major
#pragma unroll
    for (int i = 0; i < 3; i++) o[9 + i] = trans_fix[(1 + d) * 3 + i];
    const float m = mass_g[1 + d];
    const float c0 = com_g[(1 + d) * 3 + 0];
    const float c1 = com_g[(1 + d) * 3 + 1];
    const float c2 = com_g[(1 + d) * 3 + 2];
    const float* I = inertia_g + (1 + d) * 9;
    o[12] = I[0] + m * (c1 * c1 + c2 * c2);
    o[13] = I[1] - m * c0 * c1;
    o[14] = I[2] - m * c0 * c2;
    o[15] = I[4] + m * (c0 * c0 + c2 * c2);
    o[16] = I[5] - m * c1 * c2;
    o[17] = I[8] + m * (c0 * c0 + c1 * c1);
    o[18] = m;
    o[19] = m * c0;
    o[20] = m * c1;
    o[21] = m * c2;
    o[22] = damping_g[d];
    o[23] = 0.f;
}

// AX: 0 = +z, 1 = +y, 2 = -y   (joint_axes is a literal in the reference)
template <int AX>
__device__ __forceinline__ void make_R(PV3 Fc0, PV3 Fc1, PV3 Fc2, f32x2 s, f32x2 c,
                                       PV3& R0, PV3& R1, PV3& R2) {
    if (AX == 0) {          // Rq_z cols: (c,s,0), (-s,c,0), (0,0,1)
        R0 = c * Fc0 + s * Fc1;
        R1 = c * Fc1 - s * Fc0;
        R2 = Fc2;
    } else if (AX == 1) {   // Rq_y cols: (c,0,-s), (0,1,0), (s,0,c)
        R0 = c * Fc0 - s * Fc2;
        R1 = Fc1;
        R2 = s * Fc0 + c * Fc2;
    } else {                // Rq_-y cols: (c,0,s), (0,1,0), (-s,0,c)
        R0 = c * Fc0 + s * Fc2;
        R1 = Fc1;
        R2 = c * Fc2 - s * Fc0;
    }
}

// fwd: both rows in one packed pass; constants wave-uniform (broadcast).
template <int AX>
__device__ __forceinline__ void fwd_step(float4 A0, float4 A1, float4 A2, float4 A3,
                                         float4 A4, float4 A5, f32x2 s, f32x2 c,
                                         f32x2 qd, f32x2 qdd, PV3& vl, PV3& va, PV3& al,
                                         PV3& aa, PV3& fl, PV3& fa) {
    const PV3 Fc0 = uv(A0.x, A0.y, A0.z);
    const PV3 Fc1 = uv(A0.w, A1.x, A1.y);
    const PV3 Fc2 = uv(A1.z, A1.w, A2.x);
    const PV3 p = uv(A2.y, A2.z, A2.w);
    const f32x2 I00 = splat(A3.x), I01 = splat(A3.y), I02 = splat(A3.z);
    const f32x2 I11 = splat(A3.w), I12 = splat(A4.x), I22 = splat(A4.y);
    const f32x2 m = splat(A4.z);
    const PV3 mc = uv(A4.w, A5.x, A5.y);

    PV3 R0, R1, R2;
    make_R<AX>(Fc0, Fc1, Fc2, s, c, R0, R1, R2);

    // Rt(vl) + cross(-Rt p, Rt va) == Rt(vl + va x p)
    PV3 w1 = vl + cross(va, p);
    PV3 w2 = al + cross(aa, p);
    PV3 nvl{dot(R0, w1), dot(R1, w1), dot(R2, w1)};
    PV3 nva{dot(R0, va), dot(R1, va), dot(R2, va)};
    PV3 nal{dot(R0, w2), dot(R1, w2), dot(R2, w2)};
    PV3 naa{dot(R0, aa), dot(R1, aa), dot(R2, aa)};

    if (AX == 0) {          // jv=(0,0,qd): cross(v,jv)=(v.y*qd,-v.x*qd,0)
        va = {nva.x, nva.y, nva.z + qd};
        aa = {naa.x + va.y * qd, naa.y - va.x * qd, naa.z + qdd};
        vl = nvl;
        al = {nal.x + vl.y * qd, nal.y - vl.x * qd, nal.z};
    } else if (AX == 1) {   // jv=(0,qd,0): cross(v,jv)=(-v.z*qd,0,v.x*qd)
        va = {nva.x, nva.y + qd, nva.z};
        aa = {naa.x - va.z * qd, naa.y + qdd, naa.z + va.x * qd};
        vl = nvl;
        al = {nal.x - vl.z * qd, nal.y, nal.z + vl.x * qd};
    } else {                // jv=(0,-qd,0): cross(v,jv)=(v.z*qd,0,-v.x*qd)
        va = {nva.x, nva.y - qd, nva.z};
        aa = {naa.x + va.z * qd, naa.y - qdd, naa.z - va.x * qd};
        vl = nvl;
        al = {nal.x + vl.z * qd, nal.y, nal.z - vl.x * qd};
    }

    PV3 Ial = m * al + cross(aa, mc);
    PV3 Iaa = PV3{I00 * aa.x + I01 * aa.y + I02 * aa.z,
                  I01 * aa.x + I11 * aa.y + I12 * aa.z,
                  I02 * aa.x + I12 * aa.y + I22 * aa.z} + cross(mc, al);
    PV3 Ivl = m * vl + cross(va, mc);
    PV3 Iva = PV3{I00 * va.x + I01 * va.y + I02 * va.z,
                  I01 * va.x + I11 * va.y + I12 * va.z,
                  I02 * va.x + I12 * va.y + I22 * va.z} + cross(mc, vl);
    fl = Ial + cross(va, Ivl);
    fa = Iaa + cross(va, Iva) + cross(vl, Ivl);
}

// bwd: both rows packed; updates carry, returns packed tau.
template <int AX>
__device__ __forceinline__ f32x2 bwd_core(float4 A0, float4 A1, float4 A2,
                                          f32x2 s, f32x2 c,
                                          PV3 fl, PV3 fa, PV3& cl, PV3& ca) {
    const PV3 Fc0 = uv(A0.x, A0.y, A0.z);
    const PV3 Fc1 = uv(A0.w, A1.x, A1.y);
    const PV3 Fc2 = uv(A1.z, A1.w, A2.x);
    const PV3 p = uv(A2.y, A2.z, A2.w);

    PV3 tl = fl + cl;
    PV3 ta = fa + ca;
    f32x2 tau;
    if (AX == 0) tau = ta.z;
    else if (AX == 1) tau = ta.y;
    else tau = splat(0.f) - ta.y;

    PV3 R0, R1, R2;
    make_R<AX>(Fc0, Fc1, Fc2, s, c, R0, R1, R2);
    PV3 nl = tl.x * R0 + tl.y * R1 + tl.z * R2;   // R @ tl (columns)
    PV3 na = ta.x * R0 + ta.y * R1 + ta.z * R2 + cross(p, nl);
    cl = nl;
    ca = na;
    return tau;
}

// axis id for dof d: sequence z,y,z,-y,z,y,z -> 0,1,0,2,0,1,0
__device__ __forceinline__ int axid(int d) { return (d & 1) ? ((d == 3) ? 2 : 1) : 0; }

// ---------- main kernel ----------
// PACKED dual-row loop-form O(n) RNEA.  r2-r7 invariant: dur x VALUBusy
// constant (~26 us-equiv of VALU issue) across occupancy/ILP/code-form
// changes -> the kernel sits on a VALU instruction-issue floor.  Packed
// FP32 (v_pk_*) does both rows' identical algebra in ONE instruction,
// halving issued VALU ops for ~85% of the work.  Loop form keeps the body
// I$-resident (r5 win); LDS parking/stores unchanged from r6/r7 (14.3 MB
// WRITE_SIZE verified).
__global__ __launch_bounds__(BLK) void rnea_main(
    const float* __restrict__ q_g, const float* __restrict__ qd_g,
    const float* __restrict__ qdd_g, const float* __restrict__ cst,
    float* __restrict__ out, int nbatch) {
    __shared__ __align__(16) float sC[CST_TOT];
    __shared__ f32x2 sF[SF_V2];
    const int t = threadIdx.x;
    const int rowA = blockIdx.x * RPB + t;
    const int rowB = rowA + BLK;
    const bool okA = rowA < nbatch;
    const bool okB = rowB < nbatch;
    const int rcA = okA ? rowA : (nbatch - 1);
    const int rcB = okB ? rowB : (nbatch - 1);
    const size_t goA = (size_t)rcA * NDOF;
    const size_t goB = (size_t)rcB * NDOF;

    if (t < CST_TOT / 4)   // 42 float4 = one coalesced burst
        reinterpret_cast<float4*>(sC)[t] = reinterpret_cast<const float4*>(cst)[t];
    __syncthreads();

    // ---------------- forward pass: loop over parked links 0..4 ----------------
    PV3 vl{splat(0.f), splat(0.f), splat(0.f)};
    PV3 va = vl, aa = vl;
    PV3 al{splat(0.f), splat(0.f), splat(9.81f)};
    f32x2 qn, qdn, qddn;
    qn.x = q_g[goA];   qn.y = q_g[goB];
    qdn.x = qd_g[goA]; qdn.y = qd_g[goB];
    qddn.x = qdd_g[goA]; qddn.y = qdd_g[goB];
#pragma clang loop unroll(disable)
    for (int d = 0; d < NPARK; ++d) {
        const f32x2 q = qn, qd = qdn, qdd = qddn;
        qn.x = q_g[goA + d + 1];   qn.y = q_g[goB + d + 1];     // prefetch next
        qdn.x = qd_g[goA + d + 1]; qdn.y = qd_g[goB + d + 1];
        qddn.x = qdd_g[goA + d + 1]; qddn.y = qdd_g[goB + d + 1];
        f32x2 s, c;
        s.x = __sinf(q.x); s.y = __sinf(q.y);
        c.x = __cosf(q.x); c.y = __cosf(q.y);
        const float4* C4 = reinterpret_cast<const float4*>(sC) + d * 6;
        const float4 A0 = C4[0], A1 = C4[1], A2 = C4[2], A3 = C4[3], A4 = C4[4], A5 = C4[5];
        PV3 fl, fa;
        switch (axid(d)) {
            case 0: fwd_step<0>(A0, A1, A2, A3, A4, A5, s, c, qd, qdd, vl, va, al, aa, fl, fa); break;
            case 1: fwd_step<1>(A0, A1, A2, A3, A4, A5, s, c, qd, qdd, vl, va, al, aa, fl, fa); break;
            default: fwd_step<2>(A0, A1, A2, A3, A4, A5, s, c, qd, qdd, vl, va, al, aa, fl, fa); break;
        }
        f32x2* r = sF + d * 6 * BLK + t;   // [link][comp][thread], ds_write_b64
        r[0 * BLK] = fl.x; r[1 * BLK] = fl.y; r[2 * BLK] = fl.z;
        r[3 * BLK] = fa.x; r[4 * BLK] = fa.y; r[5 * BLK] = fa.z;
    }

    // ---------------- peel: links 5,6 fwd -> immediate bwd in registers ----------
    const f32x2 q5 = qn, qd5 = qdn, qdd5 = qddn;    // prefetched above
    f32x2 q6, qd6, qdd6;
    q6.x = q_g[goA + 6];   q6.y = q_g[goB + 6];
    qd6.x = qd_g[goA + 6]; qd6.y = qd_g[goB + 6];
    qdd6.x = qdd_g[goA + 6]; qdd6.y = qdd_g[goB + 6];
    f32x2 s5, c5, s6, c6;
    s5.x = __sinf(q5.x); s5.y = __sinf(q5.y);
    c5.x = __cosf(q5.x); c5.y = __cosf(q5.y);
    s6.x = __sinf(q6.x); s6.y = __sinf(q6.y);
    c6.x = __cosf(q6.x); c6.y = __cosf(q6.y);
    PV3 cl{splat(0.f), splat(0.f), splat(0.f)}, ca = cl;
    f32x2 tau5, tau6;
    {
        const float4* C5 = reinterpret_cast<const float4*>(sC) + 5 * 6;
        const float4 B0 = C5[0], B1 = C5[1], B2 = C5[2], B3 = C5[3], B4 = C5[4], B5 = C5[5];
        const float4* C6 = reinterpret_cast<const float4*>(sC) + 6 * 6;
        const float4 D0 = C6[0], D1 = C6[1], D2 = C6[2], D3 = C6[3], D4 = C6[4], D5 = C6[5];
        PV3 fl5, fa5, fl6, fa6;
        fwd_step<1>(B0, B1, B2, B3, B4, B5, s5, c5, qd5, qdd5, vl, va, al, aa, fl5, fa5);
        fwd_step<0>(D0, D1, D2, D3, D4, D5, s6, c6, qd6, qdd6, vl, va, al, aa, fl6, fa6);
        tau6 = bwd_core<0>(D0, D1, D2, s6, c6, fl6, fa6, cl, ca) + splat(D5.z) * qd6;
        tau5 = bwd_core<1>(B0, B1, B2, s5, c5, fl5, fa5, cl, ca) + splat(B5.z) * qd5;
        // damp lives at float offset 22 == component .z of float4 #5
    }

    // ---------------- backward pass: loop over parked links 4..0 ----------------
    // same-thread LDS reuse only -> no barrier; finished packed tau overwrites
    // the just-consumed fl.x slot so all global stores issue together below.
#pragma clang loop unroll(disable)
    for (int d = NPARK - 1; d >= 0; --d) {
        f32x2 q, qd;
        q.x = q_g[goA + d];  q.y = q_g[goB + d];    // L1-hot reload
        qd.x = qd_g[goA + d]; qd.y = qd_g[goB + d];
        f32x2 s, c;
        s.x = __sinf(q.x); s.y = __sinf(q.y);
        c.x = __cosf(q.x); c.y = __cosf(q.y);
        const float4* C4 = reinterpret_cast<const float4*>(sC) + d * 6;
        const float4 A0 = C4[0], A1 = C4[1], A2 = C4[2];
        const float damp = sC[d * CST_STRIDE + 22];
        f32x2* r = sF + d * 6 * BLK + t;
        const PV3 fl{r[0 * BLK], r[1 * BLK], r[2 * BLK]};
        const PV3 fa{r[3 * BLK], r[4 * BLK], r[5 * BLK]};
        f32x2 tau;
        switch (axid(d)) {
            case 0: tau = bwd_core<0>(A0, A1, A2, s, c, fl, fa, cl, ca); break;
            case 1: tau = bwd_core<1>(A0, A1, A2, s, c, fl, fa, cl, ca); break;
            default: tau = bwd_core<2>(A0, A1, A2, s, c, fl, fa, cl, ca); break;
        }
        r[0] = tau + splat(damp) * qd;   // park finished packed tau
    }

    // ---------------- stores: all back-to-back (write-combine friendly) ---------
    if (okA) {
#pragma unroll
        for (int d = 0; d < NPARK; ++d) out[goA + d] = sF[d * 6 * BLK + t].x;
        out[goA + 5] = tau5.x;
        out[goA + 6] = tau6.x;
    }
    if (okB) {
#pragma unroll
        for (int d = 0; d < NPARK; ++d) out[goB + d] = sF[d * 6 * BLK + t].y;
        out[goB + 5] = tau5.y;
        out[goB + 6] = tau6.y;
    }
}

extern "C" void kernel_launch(void* const* d_in, const int* in_sizes, int n_in,
                              void* d_out, int out_size, void* d_ws, size_t ws_size,
                              hipStream_t stream) {
    const float* q = (const float*)d_in[0];
    const float* qd = (const float*)d_in[1];
    const float* qdd = (const float*)d_in[2];
    const float* rot_fix = (const float*)d_in[3];
    const float* trans_fix = (const float*)d_in[4];
    // d_in[5] = joint_axes: compile-time constant in the reference (z,y,z,-y,z,y,z)
    const float* mass = (const float*)d_in[6];
    const float* com = (const float*)d_in[7];
    const float* inertia = (const float*)d_in[8];
    const float* damping = (const float*)d_in[9];
    float* out = (float*)d_out;
    float* cst = (float*)d_ws;  // 7*24*4 = 672 B

    const int n_elem = in_sizes[0];  // B * 7
    const int B = n_elem / NDOF;
    const int grid = (B + RPB - 1) / RPB;

    rnea_prep<<<1, 64, 0, stream>>>(rot_fix, trans_fix, mass, com, inertia, damping, cst);
    rnea_main<<<grid, BLK, 0, stream>>>(q, qd, qdd, cst, out, B);
}